// Round 5
// baseline (349.159 us; speedup 1.0000x reference)
//
#include <hip/hip_runtime.h>
#include <hip/hip_cooperative_groups.h>
#include <math.h>

namespace cg = cooperative_groups;

// Problem constants
#define B_     16
#define S_     2048
#define H_     1024
#define NS_    64
#define NC_    4096
#define NROWS  1024   // B_*NS_
#define NTILES 32     // NC_/128
#define GRID_  256    // = #CUs = GEMM tile count; 1 block/CU (97KB LDS)

#define SCALE_ 30.0f
#define COS_M_ 0.8775825618903728f     // cos(0.5)
#define SIN_M_ 0.479425538604203f      // sin(0.5)
#define TH_    (-0.8775825618903728f)  // cos(pi-0.5)
#define MM_    0.2397127693021015f     // sin(pi-0.5)*0.5
#define LN_EPS_ 1e-7f

// ---------- helpers ----------

__device__ __forceinline__ unsigned short f2bf(float f) {
    union { float f; unsigned int u; } v; v.f = f;
    unsigned int r = v.u + 0x7fffu + ((v.u >> 16) & 1u);   // RNE
    return (unsigned short)(r >> 16);
}

__device__ __forceinline__ float block_sum(float v) {
    __shared__ float sb[4];
    #pragma unroll
    for (int off = 32; off > 0; off >>= 1) v += __shfl_down(v, off, 64);
    if ((threadIdx.x & 63) == 0) sb[threadIdx.x >> 6] = v;
    __syncthreads();
    float r = sb[0] + sb[1] + sb[2] + sb[3];
    __syncthreads();
    return r;
}

// async global->LDS, 16 bytes per lane. LDS dest must be waveBase + lane*16.
__device__ __forceinline__ void gload16(const void* g, void* l) {
    __builtin_amdgcn_global_load_lds(
        (const __attribute__((address_space(1))) unsigned int*)g,
        (__attribute__((address_space(3))) unsigned int*)l,
        16, 0, 0);
}

typedef short bf16x8 __attribute__((ext_vector_type(8)));
typedef float f32x4  __attribute__((ext_vector_type(4)));

// ---------- single cooperative kernel: norms -> grid.sync -> GEMM+CE -> combine ----------
__global__ __launch_bounds__(256, 1) void mega_kernel(
    const float* __restrict__ enc,      // [B,S,H]
    const float* __restrict__ gamma,    // [H]
    const float* __restrict__ beta,     // [H]
    const int*   __restrict__ heads,    // [B,NS]
    const int*   __restrict__ tails,    // [B,NS]
    const float* __restrict__ W,        // [NC,H]
    const int*   __restrict__ labels,   // [NROWS]
    unsigned short* __restrict__ embn,  // [NROWS,H] bf16 (ws)
    unsigned short* __restrict__ Wn,    // [NC,H] bf16 (ws)
    float* __restrict__ tmax,           // [NROWS][NTILES] (ws)
    float* __restrict__ tsum,           // [NROWS][NTILES] (ws)
    float* __restrict__ glab,           // [NROWS] (ws)
    float* __restrict__ out,            // [1]
    unsigned int* __restrict__ cnt)     // completion counter (ws, poisoned each iter)
{
    __shared__ short As[3][128 * 64];   // GEMM triple-buffer, 48KB
    __shared__ short Bs[3][128 * 64];   // 48KB (total 96KB)
    __shared__ float smx[2][128];       // cross-wave row-max exchange
    __shared__ float ssm[2][128];       // cross-wave row-sum exchange
    __shared__ int   s_last;

    const int bid = blockIdx.x;         // 0..255
    const int tid = threadIdx.x;

    if (bid == 0 && tid == 0) *cnt = 0u;   // ordered before use by grid.sync

    // ================= phase 1: span mean+LN+l2norm, and wnorm =================
    // 5120 tasks grid-strided over 256 blocks -> 20 tasks/block
    // (4 span tasks + 16 wnorm tasks each: balanced mix).
    for (int task = bid; task < NROWS + NC_; task += GRID_) {
        if (task < NROWS) {
            const int span = task;
            const int b    = span >> 6;
            const int head = heads[span];
            const int tail = tails[span];
            const int cnt_ = tail - head;

            const float4* base = (const float4*)(enc + ((size_t)b * S_ + head) * H_) + tid;
            float4 a0 = {0.f,0.f,0.f,0.f}, a1 = a0, a2 = a0, a3 = a0;
            int s = 0;
            for (; s + 4 <= cnt_; s += 4) {
                float4 x0 = base[(size_t)(s + 0) * (H_ / 4)];
                float4 x1 = base[(size_t)(s + 1) * (H_ / 4)];
                float4 x2 = base[(size_t)(s + 2) * (H_ / 4)];
                float4 x3 = base[(size_t)(s + 3) * (H_ / 4)];
                a0.x += x0.x; a0.y += x0.y; a0.z += x0.z; a0.w += x0.w;
                a1.x += x1.x; a1.y += x1.y; a1.z += x1.z; a1.w += x1.w;
                a2.x += x2.x; a2.y += x2.y; a2.z += x2.z; a2.w += x2.w;
                a3.x += x3.x; a3.y += x3.y; a3.z += x3.z; a3.w += x3.w;
            }
            for (; s < cnt_; ++s) {
                float4 x = base[(size_t)s * (H_ / 4)];
                a0.x += x.x; a0.y += x.y; a0.z += x.z; a0.w += x.w;
            }
            const float inv = 1.0f / (float)cnt_;
            float v0 = (a0.x + a1.x + a2.x + a3.x) * inv;
            float v1 = (a0.y + a1.y + a2.y + a3.y) * inv;
            float v2 = (a0.z + a1.z + a2.z + a3.z) * inv;
            float v3 = (a0.w + a1.w + a2.w + a3.w) * inv;

            float mu = block_sum(v0 + v1 + v2 + v3) * (1.0f / H_);
            float d0 = v0 - mu, d1 = v1 - mu, d2 = v2 - mu, d3 = v3 - mu;
            float var = block_sum(d0*d0 + d1*d1 + d2*d2 + d3*d3) * (1.0f / H_);
            float rstd = rsqrtf(var + LN_EPS_);

            const float4 g4 = ((const float4*)gamma)[tid];
            const float4 b4 = ((const float4*)beta)[tid];
            float y0 = d0 * rstd * g4.x + b4.x;
            float y1 = d1 * rstd * g4.y + b4.y;
            float y2 = d2 * rstd * g4.z + b4.z;
            float y3 = d3 * rstd * g4.w + b4.w;

            float ss = block_sum(y0*y0 + y1*y1 + y2*y2 + y3*y3);
            float invn = 1.0f / fmaxf(sqrtf(ss), 1e-12f);

            ushort4 o;
            o.x = f2bf(y0 * invn); o.y = f2bf(y1 * invn);
            o.z = f2bf(y2 * invn); o.w = f2bf(y3 * invn);
            *(ushort4*)(embn + (size_t)span * H_ + tid * 4) = o;
        } else {
            const int row = task - NROWS;
            float4 x = ((const float4*)(W + (size_t)row * H_))[tid];
            float ss = block_sum(x.x*x.x + x.y*x.y + x.z*x.z + x.w*x.w);
            float invn = 1.0f / fmaxf(sqrtf(ss), 1e-12f);
            ushort4 o;
            o.x = f2bf(x.x * invn); o.y = f2bf(x.y * invn);
            o.z = f2bf(x.z * invn); o.w = f2bf(x.w * invn);
            *(ushort4*)(Wn + (size_t)row * H_ + tid * 4) = o;
        }
    }

    __threadfence();                 // publish embn/Wn device-wide (cross-XCD)
    cg::this_grid().sync();          // all 256 blocks resident (1 block/CU)

    // ================= phase 2: GEMM + ArcFace + per-tile softmax partials =================
    // 128x128 tile/block, BK=64, triple-buffered LDS, depth-2 prefetch with
    // counted vmcnt(8). Bijective XCD swizzle (256 blocks, 256%8==0).
    {
        const int swz = (bid & 7) * 32 + (bid >> 3);
        const int m0  = (swz & 7) * 128;
        const int nt  = swz >> 3;            // n-tile index 0..31
        const int n0  = nt * 128;

        const int lane = tid & 63;
        const int w    = tid >> 6;
        const int wm   = (w & 1) * 64;
        const int wnh  = w >> 1;             // 0/1
        const int wn   = wnh * 64;
        const int lrow = lane & 15;
        const int q    = lane >> 4;
        const int xr   = lrow & 7;           // read-side XOR key

        f32x4 acc[4][4];
        #pragma unroll
        for (int i = 0; i < 4; ++i)
            #pragma unroll
            for (int j = 0; j < 4; ++j)
                acc[i][j] = (f32x4){0.f, 0.f, 0.f, 0.f};

        const unsigned short* A  = embn;
        const unsigned short* Bw = Wn;

        auto stage = [&](int bsel, int k0) {
            #pragma unroll
            for (int h = 0; h < 4; ++h) {
                const int s   = tid + h * 256;
                const int row = s >> 3;
                const int s16 = (s & 7) ^ (row & 7);
                gload16(A  + (size_t)(m0 + row) * 1024 + k0 + s16 * 8, &As[bsel][s * 8]);
                gload16(Bw + (size_t)(n0 + row) * 1024 + k0 + s16 * 8, &Bs[bsel][s * 8]);
            }
        };

        auto compute = [&](int bsel) {
            #pragma unroll
            for (int kk = 0; kk < 2; ++kk) {
                const int c16 = ((kk << 2) | q) ^ xr;   // swizzled 16B column
                bf16x8 af[4], bfr[4];
                #pragma unroll
                for (int i = 0; i < 4; ++i)
                    af[i] = *(const bf16x8*)(&As[bsel][(wm + i * 16 + lrow) * 64 + c16 * 8]);
                #pragma unroll
                for (int j = 0; j < 4; ++j)
                    bfr[j] = *(const bf16x8*)(&Bs[bsel][(wn + j * 16 + lrow) * 64 + c16 * 8]);
                #pragma unroll
                for (int i = 0; i < 4; ++i)
                    #pragma unroll
                    for (int j = 0; j < 4; ++j)
                        acc[i][j] = __builtin_amdgcn_mfma_f32_16x16x32_bf16(af[i], bfr[j], acc[i][j], 0, 0, 0);
            }
        };

        stage(0, 0);
        stage(1, 64);
        asm volatile("s_waitcnt vmcnt(8)" ::: "memory");   // tile0 landed, tile1 flying
        __builtin_amdgcn_s_barrier();
        __builtin_amdgcn_sched_barrier(0);

        int cur = 0, nxt = 1, fut = 2;
        for (int t = 0; t < 14; ++t) {
            stage(fut, (t + 2) * 64);                      // depth-2 prefetch
            compute(cur);
            asm volatile("s_waitcnt vmcnt(8)" ::: "memory");  // t+1 landed; t+2 flying
            __builtin_amdgcn_s_barrier();
            __builtin_amdgcn_sched_barrier(0);
            const int tmp = cur; cur = nxt; nxt = fut; fut = tmp;
        }
        compute(cur);                                      // tile 14
        asm volatile("s_waitcnt vmcnt(0)" ::: "memory");   // drain tile 15
        __builtin_amdgcn_s_barrier();
        __builtin_amdgcn_sched_barrier(0);
        compute(nxt);                                      // tile 15

        // ---- fused epilogue: arcface fix + per-row tile max/sumexp ----
        int lab[4][4];
        #pragma unroll
        for (int i = 0; i < 4; ++i)
            #pragma unroll
            for (int r2 = 0; r2 < 4; ++r2)
                lab[i][r2] = labels[m0 + wm + i * 16 + q * 4 + r2];

        #pragma unroll
        for (int i = 0; i < 4; ++i)
            #pragma unroll
            for (int r2 = 0; r2 < 4; ++r2) {
                const int gcol_base = n0 + wn;
                #pragma unroll
                for (int j = 0; j < 4; ++j) {
                    const int col = gcol_base + j * 16 + lrow;
                    float c = acc[i][j][r2];
                    float logit;
                    if (col == lab[i][r2]) {
                        float sine = sqrtf(fmaxf(1.0f - c * c, 0.0f));
                        float phi  = c * COS_M_ - sine * SIN_M_;
                        logit = ((c > TH_) ? phi : (c - MM_)) * SCALE_;
                        glab[m0 + wm + i * 16 + q * 4 + r2] = logit;
                    } else {
                        logit = c * SCALE_;
                    }
                    acc[i][j][r2] = logit;
                }
            }

        float mrow[4][4];
        #pragma unroll
        for (int i = 0; i < 4; ++i)
            #pragma unroll
            for (int r2 = 0; r2 < 4; ++r2) {
                float m = fmaxf(fmaxf(acc[i][0][r2], acc[i][1][r2]),
                                fmaxf(acc[i][2][r2], acc[i][3][r2]));
                #pragma unroll
                for (int mk = 1; mk <= 8; mk <<= 1)
                    m = fmaxf(m, __shfl_xor(m, mk, 64));
                mrow[i][r2] = m;
            }

        if (lrow == 0) {
            #pragma unroll
            for (int i = 0; i < 4; ++i)
                #pragma unroll
                for (int r2 = 0; r2 < 4; ++r2)
                    smx[wnh][wm + i * 16 + q * 4 + r2] = mrow[i][r2];
        }
        __syncthreads();
        float M[4][4];
        #pragma unroll
        for (int i = 0; i < 4; ++i)
            #pragma unroll
            for (int r2 = 0; r2 < 4; ++r2)
                M[i][r2] = fmaxf(mrow[i][r2], smx[wnh ^ 1][wm + i * 16 + q * 4 + r2]);

        float srow[4][4];
        #pragma unroll
        for (int i = 0; i < 4; ++i)
            #pragma unroll
            for (int r2 = 0; r2 < 4; ++r2) {
                float s = expf(acc[i][0][r2] - M[i][r2]) + expf(acc[i][1][r2] - M[i][r2])
                        + expf(acc[i][2][r2] - M[i][r2]) + expf(acc[i][3][r2] - M[i][r2]);
                #pragma unroll
                for (int mk = 1; mk <= 8; mk <<= 1)
                    s += __shfl_xor(s, mk, 64);
                srow[i][r2] = s;
            }
        if (lrow == 0) {
            #pragma unroll
            for (int i = 0; i < 4; ++i)
                #pragma unroll
                for (int r2 = 0; r2 < 4; ++r2)
                    ssm[wnh][wm + i * 16 + q * 4 + r2] = srow[i][r2];
        }
        __syncthreads();
        if (wnh == 0 && lrow == 0) {
            #pragma unroll
            for (int i = 0; i < 4; ++i)
                #pragma unroll
                for (int r2 = 0; r2 < 4; ++r2) {
                    const int rl = wm + i * 16 + q * 4 + r2;
                    const int R  = m0 + rl;
                    tmax[(size_t)R * NTILES + nt] = M[i][r2];
                    tsum[(size_t)R * NTILES + nt] = srow[i][r2] + ssm[1][rl];
                }
        }
    }

    // ================= phase 3: last block combines partials -> mean =================
    if (tid == 0) {
        __threadfence();                               // publish tmax/tsum/glab
        s_last = (atomicAdd(cnt, 1u) == GRID_ - 1);
    }
    __syncthreads();
    if (s_last) {
        __threadfence();                               // acquire
        float acc_nll = 0.f;
        #pragma unroll
        for (int t = 0; t < 4; ++t) {
            const int row = tid + t * 256;
            const float4* mx4 = (const float4*)(tmax + (size_t)row * NTILES);
            const float4* sm4 = (const float4*)(tsum + (size_t)row * NTILES);
            float4 mv[8], sv[8];
            #pragma unroll
            for (int k = 0; k < 8; ++k) { mv[k] = mx4[k]; sv[k] = sm4[k]; }

            float gm = -1e30f;
            #pragma unroll
            for (int k = 0; k < 8; ++k)
                gm = fmaxf(gm, fmaxf(fmaxf(mv[k].x, mv[k].y), fmaxf(mv[k].z, mv[k].w)));

            float se = 0.f;
            #pragma unroll
            for (int k = 0; k < 8; ++k) {
                se += sv[k].x * expf(mv[k].x - gm);
                se += sv[k].y * expf(mv[k].y - gm);
                se += sv[k].z * expf(mv[k].z - gm);
                se += sv[k].w * expf(mv[k].w - gm);
            }
            acc_nll += logf(se) + gm - glab[row];
        }
        float tot = block_sum(acc_nll);
        if (tid == 0) out[0] = tot * (1.0f / NROWS);   // deterministic final sum
    }
}

// ---------- launch ----------
extern "C" void kernel_launch(void* const* d_in, const int* in_sizes, int n_in,
                              void* d_out, int out_size, void* d_ws, size_t ws_size,
                              hipStream_t stream) {
    const float* enc    = (const float*)d_in[0];
    const float* gamma  = (const float*)d_in[1];
    const float* beta   = (const float*)d_in[2];
    const float* W      = (const float*)d_in[3];
    const int*   heads  = (const int*)d_in[4];
    const int*   tails  = (const int*)d_in[5];
    const int*   labels = (const int*)d_in[6];
    float* out = (float*)d_out;

    char* ws = (char*)d_ws;
    unsigned short* embn = (unsigned short*)(ws);                           // 2 MB
    unsigned short* Wn   = (unsigned short*)(ws + (2u  << 20));             // 8 MB
    float* tmax          = (float*)        (ws + (10u << 20));              // 128 KB
    float* tsum          = (float*)        (ws + (10u << 20) + (128u<<10)); // 128 KB
    float* glab          = (float*)        (ws + (10u << 20) + (256u<<10)); // 4 KB
    unsigned int* cnt    = (unsigned int*) (ws + (10u << 20) + (260u<<10)); // 4 B

    void* args[] = { (void*)&enc, (void*)&gamma, (void*)&beta, (void*)&heads,
                     (void*)&tails, (void*)&W, (void*)&labels, (void*)&embn,
                     (void*)&Wn, (void*)&tmax, (void*)&tsum, (void*)&glab,
                     (void*)&out, (void*)&cnt };
    hipLaunchCooperativeKernel((const void*)mega_kernel, dim3(GRID_), dim3(256),
                               args, 0, stream);
}

// Round 6
// 240.139 us; speedup vs baseline: 1.4540x; 1.4540x over previous
//
#include <hip/hip_runtime.h>
#include <math.h>

// Problem constants
#define B_     16
#define S_     2048
#define H_     1024
#define NS_    64
#define NC_    4096
#define NROWS  1024   // B_*NS_
#define NTILES 32     // NC_/128

#define SCALE_ 30.0f
#define COS_M_ 0.8775825618903728f     // cos(0.5)
#define SIN_M_ 0.479425538604203f      // sin(0.5)
#define TH_    (-0.8775825618903728f)  // cos(pi-0.5)
#define MM_    0.2397127693021015f     // sin(pi-0.5)*0.5
#define LN_EPS_ 1e-7f

// ---------- helpers ----------

__device__ __forceinline__ unsigned short f2bf(float f) {
    union { float f; unsigned int u; } v; v.f = f;
    unsigned int r = v.u + 0x7fffu + ((v.u >> 16) & 1u);   // RNE
    return (unsigned short)(r >> 16);
}

__device__ __forceinline__ float block_sum(float v) {
    __shared__ float sb[4];
    #pragma unroll
    for (int off = 32; off > 0; off >>= 1) v += __shfl_down(v, off, 64);
    if ((threadIdx.x & 63) == 0) sb[threadIdx.x >> 6] = v;
    __syncthreads();
    float r = sb[0] + sb[1] + sb[2] + sb[3];
    __syncthreads();
    return r;
}

// async global->LDS, 16 bytes per lane. LDS dest must be waveBase + lane*16.
__device__ __forceinline__ void gload16(const void* g, void* l) {
    __builtin_amdgcn_global_load_lds(
        (const __attribute__((address_space(1))) unsigned int*)g,
        (__attribute__((address_space(3))) unsigned int*)l,
        16, 0, 0);
}

typedef short bf16x8 __attribute__((ext_vector_type(8)));
typedef float f32x4  __attribute__((ext_vector_type(4)));

// ---------- K1: fused (span mean + LN + l2norm) and (wnorm); zeroes counter ----------
// 5120 independent small-LDS blocks -> ~8 blocks/CU resident, BW-bound
// (the R5 mega-kernel proved this phase collapses to 0.4 TB/s at 1 block/CU).
__global__ __launch_bounds__(256) void fused_norm_kernel(
    const float* __restrict__ enc,      // [B,S,H]
    const float* __restrict__ gamma,    // [H]
    const float* __restrict__ beta,     // [H]
    const int*   __restrict__ heads,    // [B,NS]
    const int*   __restrict__ tails,    // [B,NS]
    const float* __restrict__ W,        // [NC,H]
    unsigned short* __restrict__ embn,  // [NROWS,H] bf16
    unsigned short* __restrict__ Wn,    // [NC,H] bf16
    unsigned int*   __restrict__ cnt)   // combine completion counter (ws poisoned every iter)
{
    const int tid = threadIdx.x;
    if (blockIdx.x == 0 && tid == 0) *cnt = 0u;

    if (blockIdx.x < NROWS) {
        const int span = blockIdx.x;
        const int b    = span >> 6;
        const int head = heads[span];
        const int tail = tails[span];
        const int cnt_ = tail - head;

        const float4* base = (const float4*)(enc + ((size_t)b * S_ + head) * H_) + tid;
        float4 a0 = {0.f,0.f,0.f,0.f}, a1 = a0, a2 = a0, a3 = a0;
        int s = 0;
        for (; s + 4 <= cnt_; s += 4) {
            float4 x0 = base[(size_t)(s + 0) * (H_ / 4)];
            float4 x1 = base[(size_t)(s + 1) * (H_ / 4)];
            float4 x2 = base[(size_t)(s + 2) * (H_ / 4)];
            float4 x3 = base[(size_t)(s + 3) * (H_ / 4)];
            a0.x += x0.x; a0.y += x0.y; a0.z += x0.z; a0.w += x0.w;
            a1.x += x1.x; a1.y += x1.y; a1.z += x1.z; a1.w += x1.w;
            a2.x += x2.x; a2.y += x2.y; a2.z += x2.z; a2.w += x2.w;
            a3.x += x3.x; a3.y += x3.y; a3.z += x3.z; a3.w += x3.w;
        }
        for (; s < cnt_; ++s) {
            float4 x = base[(size_t)s * (H_ / 4)];
            a0.x += x.x; a0.y += x.y; a0.z += x.z; a0.w += x.w;
        }
        const float inv = 1.0f / (float)cnt_;
        float v0 = (a0.x + a1.x + a2.x + a3.x) * inv;
        float v1 = (a0.y + a1.y + a2.y + a3.y) * inv;
        float v2 = (a0.z + a1.z + a2.z + a3.z) * inv;
        float v3 = (a0.w + a1.w + a2.w + a3.w) * inv;

        float mu = block_sum(v0 + v1 + v2 + v3) * (1.0f / H_);
        float d0 = v0 - mu, d1 = v1 - mu, d2 = v2 - mu, d3 = v3 - mu;
        float var = block_sum(d0*d0 + d1*d1 + d2*d2 + d3*d3) * (1.0f / H_);
        float rstd = rsqrtf(var + LN_EPS_);

        const float4 g4 = ((const float4*)gamma)[tid];
        const float4 b4 = ((const float4*)beta)[tid];
        float y0 = d0 * rstd * g4.x + b4.x;
        float y1 = d1 * rstd * g4.y + b4.y;
        float y2 = d2 * rstd * g4.z + b4.z;
        float y3 = d3 * rstd * g4.w + b4.w;

        float ss = block_sum(y0*y0 + y1*y1 + y2*y2 + y3*y3);
        float invn = 1.0f / fmaxf(sqrtf(ss), 1e-12f);

        ushort4 o;
        o.x = f2bf(y0 * invn); o.y = f2bf(y1 * invn);
        o.z = f2bf(y2 * invn); o.w = f2bf(y3 * invn);
        *(ushort4*)(embn + (size_t)span * H_ + tid * 4) = o;
    } else {
        const int row = blockIdx.x - NROWS;
        float4 x = ((const float4*)(W + (size_t)row * H_))[tid];
        float ss = block_sum(x.x*x.x + x.y*x.y + x.z*x.z + x.w*x.w);
        float invn = 1.0f / fmaxf(sqrtf(ss), 1e-12f);
        ushort4 o;
        o.x = f2bf(x.x * invn); o.y = f2bf(x.y * invn);
        o.z = f2bf(x.z * invn); o.w = f2bf(x.w * invn);
        *(ushort4*)(Wn + (size_t)row * H_ + tid * 4) = o;
    }
}

// ---------- K2: fused GEMM + ArcFace + softmax partials + last-block combine ----------
// cosine tile (128x128) never touches memory. Per row of each tile: tile-max
// and tile-sumexp (ArcFace fix at label column) -> tmax/tsum; label logit ->
// glab. The LAST finishing block (device atomic counter) combines all
// partials into the final mean (deterministic order). 256 thr, BK=64,
// triple-buffered LDS (96KB), depth-2 prefetch, counted vmcnt(8) (never 0
// mid-loop). Grid = 256 = #CUs. Bijective XCD swizzle (256%8==0).
__global__ __launch_bounds__(256, 1) void gemm_ce_kernel(
    const unsigned short* __restrict__ A,   // [1024,1024] bf16 row-major
    const unsigned short* __restrict__ Bw,  // [4096,1024] bf16 row-major
    const int*   __restrict__ labels,       // [NROWS]
    float* __restrict__ tmax,               // [NROWS][NTILES]
    float* __restrict__ tsum,               // [NROWS][NTILES]
    float* __restrict__ glab,               // [NROWS]
    float* __restrict__ out,                // [1] final mean
    unsigned int* __restrict__ cnt)         // zeroed by K1
{
    __shared__ short As[3][128 * 64];   // 16KB per buffer
    __shared__ short Bs[3][128 * 64];   // 96KB total
    __shared__ float smx[2][128];       // cross-wave row-max exchange
    __shared__ float ssm[2][128];       // cross-wave row-sum exchange
    __shared__ int   s_last;

    const int bid = blockIdx.y * 8 + blockIdx.x;
    const int swz = (bid & 7) * 32 + (bid >> 3);
    const int m0  = (swz & 7) * 128;
    const int nt  = swz >> 3;            // n-tile index 0..31
    const int n0  = nt * 128;

    const int tid  = threadIdx.x;
    const int lane = tid & 63;
    const int w    = tid >> 6;
    const int wm   = (w & 1) * 64;
    const int wnh  = w >> 1;             // 0/1
    const int wn   = wnh * 64;
    const int lrow = lane & 15;
    const int q    = lane >> 4;
    const int xr   = lrow & 7;           // read-side XOR key

    f32x4 acc[4][4];
    #pragma unroll
    for (int i = 0; i < 4; ++i)
        #pragma unroll
        for (int j = 0; j < 4; ++j)
            acc[i][j] = (f32x4){0.f, 0.f, 0.f, 0.f};

    auto stage = [&](int bsel, int k0) {
        #pragma unroll
        for (int h = 0; h < 4; ++h) {
            const int s   = tid + h * 256;
            const int row = s >> 3;
            const int s16 = (s & 7) ^ (row & 7);
            gload16(A  + (size_t)(m0 + row) * 1024 + k0 + s16 * 8, &As[bsel][s * 8]);
            gload16(Bw + (size_t)(n0 + row) * 1024 + k0 + s16 * 8, &Bs[bsel][s * 8]);
        }
    };

    auto compute = [&](int bsel) {
        #pragma unroll
        for (int kk = 0; kk < 2; ++kk) {
            const int c16 = ((kk << 2) | q) ^ xr;   // swizzled 16B column
            bf16x8 af[4], bfr[4];
            #pragma unroll
            for (int i = 0; i < 4; ++i)
                af[i] = *(const bf16x8*)(&As[bsel][(wm + i * 16 + lrow) * 64 + c16 * 8]);
            #pragma unroll
            for (int j = 0; j < 4; ++j)
                bfr[j] = *(const bf16x8*)(&Bs[bsel][(wn + j * 16 + lrow) * 64 + c16 * 8]);
            #pragma unroll
            for (int i = 0; i < 4; ++i)
                #pragma unroll
                for (int j = 0; j < 4; ++j)
                    acc[i][j] = __builtin_amdgcn_mfma_f32_16x16x32_bf16(af[i], bfr[j], acc[i][j], 0, 0, 0);
        }
    };

    // prologue: tiles 0 and 1 in flight (8 loads/thread each)
    stage(0, 0);
    stage(1, 64);
    asm volatile("s_waitcnt vmcnt(8)" ::: "memory");   // tile0 landed, tile1 flying
    __builtin_amdgcn_s_barrier();
    __builtin_amdgcn_sched_barrier(0);

    int cur = 0, nxt = 1, fut = 2;
    for (int t = 0; t < 14; ++t) {
        stage(fut, (t + 2) * 64);                      // depth-2 prefetch
        compute(cur);
        asm volatile("s_waitcnt vmcnt(8)" ::: "memory");  // t+1 landed; t+2 flying
        __builtin_amdgcn_s_barrier();
        __builtin_amdgcn_sched_barrier(0);
        const int tmp = cur; cur = nxt; nxt = fut; fut = tmp;
    }
    compute(cur);                                      // tile 14
    asm volatile("s_waitcnt vmcnt(0)" ::: "memory");   // drain tile 15
    __builtin_amdgcn_s_barrier();
    __builtin_amdgcn_sched_barrier(0);
    compute(nxt);                                      // tile 15

    // ---- fused epilogue: arcface fix + per-row tile max/sumexp ----
    int lab[4][4];
    #pragma unroll
    for (int i = 0; i < 4; ++i)
        #pragma unroll
        for (int r2 = 0; r2 < 4; ++r2)
            lab[i][r2] = labels[m0 + wm + i * 16 + q * 4 + r2];

    #pragma unroll
    for (int i = 0; i < 4; ++i)
        #pragma unroll
        for (int r2 = 0; r2 < 4; ++r2) {
            const int gcol_base = n0 + wn;
            #pragma unroll
            for (int j = 0; j < 4; ++j) {
                const int col = gcol_base + j * 16 + lrow;
                float c = acc[i][j][r2];
                float logit;
                if (col == lab[i][r2]) {
                    float sine = sqrtf(fmaxf(1.0f - c * c, 0.0f));
                    float phi  = c * COS_M_ - sine * SIN_M_;
                    logit = ((c > TH_) ? phi : (c - MM_)) * SCALE_;
                    glab[m0 + wm + i * 16 + q * 4 + r2] = logit;
                } else {
                    logit = c * SCALE_;
                }
                acc[i][j][r2] = logit;
            }
        }

    float mrow[4][4];
    #pragma unroll
    for (int i = 0; i < 4; ++i)
        #pragma unroll
        for (int r2 = 0; r2 < 4; ++r2) {
            float m = fmaxf(fmaxf(acc[i][0][r2], acc[i][1][r2]),
                            fmaxf(acc[i][2][r2], acc[i][3][r2]));
            #pragma unroll
            for (int mk = 1; mk <= 8; mk <<= 1)
                m = fmaxf(m, __shfl_xor(m, mk, 64));
            mrow[i][r2] = m;
        }

    if (lrow == 0) {
        #pragma unroll
        for (int i = 0; i < 4; ++i)
            #pragma unroll
            for (int r2 = 0; r2 < 4; ++r2)
                smx[wnh][wm + i * 16 + q * 4 + r2] = mrow[i][r2];
    }
    __syncthreads();
    float M[4][4];
    #pragma unroll
    for (int i = 0; i < 4; ++i)
        #pragma unroll
        for (int r2 = 0; r2 < 4; ++r2)
            M[i][r2] = fmaxf(mrow[i][r2], smx[wnh ^ 1][wm + i * 16 + q * 4 + r2]);

    float srow[4][4];
    #pragma unroll
    for (int i = 0; i < 4; ++i)
        #pragma unroll
        for (int r2 = 0; r2 < 4; ++r2) {
            float s = expf(acc[i][0][r2] - M[i][r2]) + expf(acc[i][1][r2] - M[i][r2])
                    + expf(acc[i][2][r2] - M[i][r2]) + expf(acc[i][3][r2] - M[i][r2]);
            #pragma unroll
            for (int mk = 1; mk <= 8; mk <<= 1)
                s += __shfl_xor(s, mk, 64);
            srow[i][r2] = s;
        }
    if (lrow == 0) {
        #pragma unroll
        for (int i = 0; i < 4; ++i)
            #pragma unroll
            for (int r2 = 0; r2 < 4; ++r2)
                ssm[wnh][wm + i * 16 + q * 4 + r2] = srow[i][r2];
    }
    __syncthreads();
    if (wnh == 0 && lrow == 0) {
        #pragma unroll
        for (int i = 0; i < 4; ++i)
            #pragma unroll
            for (int r2 = 0; r2 < 4; ++r2) {
                const int rl = wm + i * 16 + q * 4 + r2;
                const int R  = m0 + rl;
                tmax[(size_t)R * NTILES + nt] = M[i][r2];
                tsum[(size_t)R * NTILES + nt] = srow[i][r2] + ssm[1][rl];
            }
    }

    // ---- last-finishing block combines all partials -> mean ----
    __syncthreads();                                   // all block stores issued
    if (tid == 0) {
        __threadfence();                               // publish tmax/tsum/glab
        s_last = (atomicAdd(cnt, 1u) == 256 - 1);
    }
    __syncthreads();
    if (s_last) {
        __threadfence();                               // acquire
        float acc_nll = 0.f;
        #pragma unroll
        for (int t = 0; t < 4; ++t) {
            const int row = tid + t * 256;
            const float4* mx4 = (const float4*)(tmax + (size_t)row * NTILES);
            const float4* sm4 = (const float4*)(tsum + (size_t)row * NTILES);
            float4 mv[8], sv[8];
            #pragma unroll
            for (int k = 0; k < 8; ++k) { mv[k] = mx4[k]; sv[k] = sm4[k]; }

            float gm = -1e30f;
            #pragma unroll
            for (int k = 0; k < 8; ++k)
                gm = fmaxf(gm, fmaxf(fmaxf(mv[k].x, mv[k].y), fmaxf(mv[k].z, mv[k].w)));

            float se = 0.f;
            #pragma unroll
            for (int k = 0; k < 8; ++k) {
                se += sv[k].x * expf(mv[k].x - gm);
                se += sv[k].y * expf(mv[k].y - gm);
                se += sv[k].z * expf(mv[k].z - gm);
                se += sv[k].w * expf(mv[k].w - gm);
            }
            acc_nll += logf(se) + gm - glab[row];
        }
        float tot = block_sum(acc_nll);
        if (tid == 0) out[0] = tot * (1.0f / NROWS);   // deterministic final sum
    }
}

// ---------- launch ----------
extern "C" void kernel_launch(void* const* d_in, const int* in_sizes, int n_in,
                              void* d_out, int out_size, void* d_ws, size_t ws_size,
                              hipStream_t stream) {
    const float* enc    = (const float*)d_in[0];
    const float* gamma  = (const float*)d_in[1];
    const float* beta   = (const float*)d_in[2];
    const float* W      = (const float*)d_in[3];
    const int*   heads  = (const int*)d_in[4];
    const int*   tails  = (const int*)d_in[5];
    const int*   labels = (const int*)d_in[6];
    float* out = (float*)d_out;

    char* ws = (char*)d_ws;
    unsigned short* embn = (unsigned short*)(ws);                           // 2 MB
    unsigned short* Wn   = (unsigned short*)(ws + (2u  << 20));             // 8 MB
    float* tmax          = (float*)        (ws + (10u << 20));              // 128 KB
    float* tsum          = (float*)        (ws + (10u << 20) + (128u<<10)); // 128 KB
    float* glab          = (float*)        (ws + (10u << 20) + (256u<<10)); // 4 KB
    unsigned int* cnt    = (unsigned int*) (ws + (10u << 20) + (260u<<10)); // 4 B

    fused_norm_kernel<<<NROWS + NC_, 256, 0, stream>>>(enc, gamma, beta, heads, tails, W, embn, Wn, cnt);
    dim3 g3(8, 32);
    gemm_ce_kernel <<<g3, 256, 0, stream>>>(embn, Wn, labels, tmax, tsum, glab, out, cnt);
}

// Round 7
// 227.639 us; speedup vs baseline: 1.5338x; 1.0549x over previous
//
#include <hip/hip_runtime.h>
#include <math.h>

// Problem constants
#define B_     16
#define S_     2048
#define H_     1024
#define NS_    64
#define NC_    4096
#define NROWS  1024   // B_*NS_
#define NTILES 32     // NC_/128

#define SCALE_ 30.0f
#define COS_M_ 0.8775825618903728f     // cos(0.5)
#define SIN_M_ 0.479425538604203f      // sin(0.5)
#define TH_    (-0.8775825618903728f)  // cos(pi-0.5)
#define MM_    0.2397127693021015f     // sin(pi-0.5)*0.5
#define LN_EPS_ 1e-7f

// ---------- helpers ----------

__device__ __forceinline__ unsigned short f2bf(float f) {
    union { float f; unsigned int u; } v; v.f = f;
    unsigned int r = v.u + 0x7fffu + ((v.u >> 16) & 1u);   // RNE
    return (unsigned short)(r >> 16);
}

__device__ __forceinline__ float block_sum(float v) {
    __shared__ float sb[4];
    #pragma unroll
    for (int off = 32; off > 0; off >>= 1) v += __shfl_down(v, off, 64);
    if ((threadIdx.x & 63) == 0) sb[threadIdx.x >> 6] = v;
    __syncthreads();
    float r = sb[0] + sb[1] + sb[2] + sb[3];
    __syncthreads();
    return r;
}

// async global->LDS, 16 bytes per lane. LDS dest must be waveBase + lane*16.
__device__ __forceinline__ void gload16(const void* g, void* l) {
    __builtin_amdgcn_global_load_lds(
        (const __attribute__((address_space(1))) unsigned int*)g,
        (__attribute__((address_space(3))) unsigned int*)l,
        16, 0, 0);
}

typedef short bf16x8 __attribute__((ext_vector_type(8)));
typedef float f32x4  __attribute__((ext_vector_type(4)));

// ---------- K1: fused (span mean + LN + l2norm) and (wnorm); zeroes counter ----------
// 5120 independent small-LDS blocks -> ~8 blocks/CU resident, BW-bound
// (the R5 mega-kernel proved this phase collapses to 0.4 TB/s at 1 block/CU).
__global__ __launch_bounds__(256) void fused_norm_kernel(
    const float* __restrict__ enc,      // [B,S,H]
    const float* __restrict__ gamma,    // [H]
    const float* __restrict__ beta,     // [H]
    const int*   __restrict__ heads,    // [B,NS]
    const int*   __restrict__ tails,    // [B,NS]
    const float* __restrict__ W,        // [NC,H]
    unsigned short* __restrict__ embn,  // [NROWS,H] bf16
    unsigned short* __restrict__ Wn,    // [NC,H] bf16
    unsigned int*   __restrict__ cnt)   // combine completion counter (ws poisoned every iter)
{
    const int tid = threadIdx.x;
    if (blockIdx.x == 0 && tid == 0) *cnt = 0u;

    if (blockIdx.x < NROWS) {
        const int span = blockIdx.x;
        const int b    = span >> 6;
        const int head = heads[span];
        const int tail = tails[span];
        const int cnt_ = tail - head;

        const float4* base = (const float4*)(enc + ((size_t)b * S_ + head) * H_) + tid;
        float4 a0 = {0.f,0.f,0.f,0.f}, a1 = a0, a2 = a0, a3 = a0;
        int s = 0;
        for (; s + 4 <= cnt_; s += 4) {
            float4 x0 = base[(size_t)(s + 0) * (H_ / 4)];
            float4 x1 = base[(size_t)(s + 1) * (H_ / 4)];
            float4 x2 = base[(size_t)(s + 2) * (H_ / 4)];
            float4 x3 = base[(size_t)(s + 3) * (H_ / 4)];
            a0.x += x0.x; a0.y += x0.y; a0.z += x0.z; a0.w += x0.w;
            a1.x += x1.x; a1.y += x1.y; a1.z += x1.z; a1.w += x1.w;
            a2.x += x2.x; a2.y += x2.y; a2.z += x2.z; a2.w += x2.w;
            a3.x += x3.x; a3.y += x3.y; a3.z += x3.z; a3.w += x3.w;
        }
        for (; s < cnt_; ++s) {
            float4 x = base[(size_t)s * (H_ / 4)];
            a0.x += x.x; a0.y += x.y; a0.z += x.z; a0.w += x.w;
        }
        const float inv = 1.0f / (float)cnt_;
        float v0 = (a0.x + a1.x + a2.x + a3.x) * inv;
        float v1 = (a0.y + a1.y + a2.y + a3.y) * inv;
        float v2 = (a0.z + a1.z + a2.z + a3.z) * inv;
        float v3 = (a0.w + a1.w + a2.w + a3.w) * inv;

        float mu = block_sum(v0 + v1 + v2 + v3) * (1.0f / H_);
        float d0 = v0 - mu, d1 = v1 - mu, d2 = v2 - mu, d3 = v3 - mu;
        float var = block_sum(d0*d0 + d1*d1 + d2*d2 + d3*d3) * (1.0f / H_);
        float rstd = rsqrtf(var + LN_EPS_);

        const float4 g4 = ((const float4*)gamma)[tid];
        const float4 b4 = ((const float4*)beta)[tid];
        float y0 = d0 * rstd * g4.x + b4.x;
        float y1 = d1 * rstd * g4.y + b4.y;
        float y2 = d2 * rstd * g4.z + b4.z;
        float y3 = d3 * rstd * g4.w + b4.w;

        float ss = block_sum(y0*y0 + y1*y1 + y2*y2 + y3*y3);
        float invn = 1.0f / fmaxf(sqrtf(ss), 1e-12f);

        ushort4 o;
        o.x = f2bf(y0 * invn); o.y = f2bf(y1 * invn);
        o.z = f2bf(y2 * invn); o.w = f2bf(y3 * invn);
        *(ushort4*)(embn + (size_t)span * H_ + tid * 4) = o;
    } else {
        const int row = blockIdx.x - NROWS;
        float4 x = ((const float4*)(W + (size_t)row * H_))[tid];
        float ss = block_sum(x.x*x.x + x.y*x.y + x.z*x.z + x.w*x.w);
        float invn = 1.0f / fmaxf(sqrtf(ss), 1e-12f);
        ushort4 o;
        o.x = f2bf(x.x * invn); o.y = f2bf(x.y * invn);
        o.z = f2bf(x.z * invn); o.w = f2bf(x.w * invn);
        *(ushort4*)(Wn + (size_t)row * H_ + tid * 4) = o;
    }
}

// ---------- K2: fused GEMM + ArcFace + per-tile softmax partials ----------
// cosine tile (128x128) is never written to memory. Per row of each tile:
// tile-max M and tile-sumexp S (arcface fix applied at label column),
// written to tmax/tsum [NROWS][NTILES]; label logit -> glab[NROWS].
// GEMM: 256 thr, BK=64, TRIPLE-buffered LDS (96KB), depth-2 prefetch with
// counted vmcnt(8) (never 0 mid-loop). Grid=256=#CUs so 1 block/CU regardless.
__global__ __launch_bounds__(256, 1) void gemm_ce_kernel(
    const unsigned short* __restrict__ A,   // [1024,1024] bf16 row-major
    const unsigned short* __restrict__ Bw,  // [4096,1024] bf16 row-major
    const int*   __restrict__ labels,       // [NROWS]
    float* __restrict__ tmax,               // [NROWS][NTILES]
    float* __restrict__ tsum,               // [NROWS][NTILES]
    float* __restrict__ glab)               // [NROWS]
{
    __shared__ short As[3][128 * 64];   // 16KB per buffer
    __shared__ short Bs[3][128 * 64];   // 96KB total
    __shared__ float smx[2][128];       // cross-wave row-max exchange
    __shared__ float ssm[2][128];       // cross-wave row-sum exchange

    // bijective XCD swizzle (256 blocks, 256%8==0)
    const int bid = blockIdx.y * 8 + blockIdx.x;
    const int swz = (bid & 7) * 32 + (bid >> 3);
    const int m0  = (swz & 7) * 128;
    const int nt  = swz >> 3;            // n-tile index 0..31
    const int n0  = nt * 128;

    const int tid  = threadIdx.x;
    const int lane = tid & 63;
    const int w    = tid >> 6;
    const int wm   = (w & 1) * 64;
    const int wnh  = w >> 1;             // 0/1 -> wn = wnh*64
    const int wn   = wnh * 64;
    const int lrow = lane & 15;
    const int q    = lane >> 4;
    const int xr   = lrow & 7;           // read-side XOR key

    f32x4 acc[4][4];
    #pragma unroll
    for (int i = 0; i < 4; ++i)
        #pragma unroll
        for (int j = 0; j < 4; ++j)
            acc[i][j] = (f32x4){0.f, 0.f, 0.f, 0.f};

    auto stage = [&](int bsel, int k0) {
        #pragma unroll
        for (int h = 0; h < 4; ++h) {
            const int s   = tid + h * 256;
            const int row = s >> 3;
            const int s16 = (s & 7) ^ (row & 7);
            gload16(A  + (size_t)(m0 + row) * 1024 + k0 + s16 * 8, &As[bsel][s * 8]);
            gload16(Bw + (size_t)(n0 + row) * 1024 + k0 + s16 * 8, &Bs[bsel][s * 8]);
        }
    };

    auto compute = [&](int bsel) {
        #pragma unroll
        for (int kk = 0; kk < 2; ++kk) {
            const int c16 = ((kk << 2) | q) ^ xr;   // swizzled 16B column
            bf16x8 af[4], bfr[4];
            #pragma unroll
            for (int i = 0; i < 4; ++i)
                af[i] = *(const bf16x8*)(&As[bsel][(wm + i * 16 + lrow) * 64 + c16 * 8]);
            #pragma unroll
            for (int j = 0; j < 4; ++j)
                bfr[j] = *(const bf16x8*)(&Bs[bsel][(wn + j * 16 + lrow) * 64 + c16 * 8]);
            #pragma unroll
            for (int i = 0; i < 4; ++i)
                #pragma unroll
                for (int j = 0; j < 4; ++j)
                    acc[i][j] = __builtin_amdgcn_mfma_f32_16x16x32_bf16(af[i], bfr[j], acc[i][j], 0, 0, 0);
        }
    };

    // prologue: tiles 0 and 1 in flight (8 loads/thread each)
    stage(0, 0);
    stage(1, 64);
    asm volatile("s_waitcnt vmcnt(8)" ::: "memory");   // tile0 landed, tile1 flying
    __builtin_amdgcn_s_barrier();
    __builtin_amdgcn_sched_barrier(0);

    int cur = 0, nxt = 1, fut = 2;
    for (int t = 0; t < 14; ++t) {
        stage(fut, (t + 2) * 64);                      // depth-2 prefetch
        compute(cur);                                  // ~2 tiles of cover for t+1
        asm volatile("s_waitcnt vmcnt(8)" ::: "memory");  // t+1 landed; t+2 flying
        __builtin_amdgcn_s_barrier();
        __builtin_amdgcn_sched_barrier(0);
        const int tmp = cur; cur = nxt; nxt = fut; fut = tmp;
    }
    compute(cur);                                      // tile 14
    asm volatile("s_waitcnt vmcnt(0)" ::: "memory");   // drain tile 15
    __builtin_amdgcn_s_barrier();
    __builtin_amdgcn_sched_barrier(0);
    compute(nxt);                                      // tile 15

    // ---- fused epilogue: arcface fix + per-row tile max/sumexp ----
    // acc[i][j][r2]: row_local = wm + i*16 + q*4 + r2, col_local = wn + j*16 + lrow

    // per-lane labels for its 16 rows (labels buffer is 4KB, L2-hot)
    int lab[4][4];
    #pragma unroll
    for (int i = 0; i < 4; ++i)
        #pragma unroll
        for (int r2 = 0; r2 < 4; ++r2)
            lab[i][r2] = labels[m0 + wm + i * 16 + q * 4 + r2];

    // logits in place (+ label-logit store; unique writer per row globally)
    #pragma unroll
    for (int i = 0; i < 4; ++i)
        #pragma unroll
        for (int r2 = 0; r2 < 4; ++r2) {
            const int gcol_base = n0 + wn;
            #pragma unroll
            for (int j = 0; j < 4; ++j) {
                const int col = gcol_base + j * 16 + lrow;
                float c = acc[i][j][r2];
                float logit;
                if (col == lab[i][r2]) {
                    float sine = sqrtf(fmaxf(1.0f - c * c, 0.0f));
                    float phi  = c * COS_M_ - sine * SIN_M_;
                    logit = ((c > TH_) ? phi : (c - MM_)) * SCALE_;
                    glab[m0 + wm + i * 16 + q * 4 + r2] = logit;
                } else {
                    logit = c * SCALE_;
                }
                acc[i][j][r2] = logit;
            }
        }

    // wave-local row max over 64 cols: j-reduce then 16-lane butterfly
    float mrow[4][4];
    #pragma unroll
    for (int i = 0; i < 4; ++i)
        #pragma unroll
        for (int r2 = 0; r2 < 4; ++r2) {
            float m = fmaxf(fmaxf(acc[i][0][r2], acc[i][1][r2]),
                            fmaxf(acc[i][2][r2], acc[i][3][r2]));
            #pragma unroll
            for (int mk = 1; mk <= 8; mk <<= 1)
                m = fmaxf(m, __shfl_xor(m, mk, 64));
            mrow[i][r2] = m;
        }

    // cross-wave (wn halves share rows): exchange via LDS
    if (lrow == 0) {
        #pragma unroll
        for (int i = 0; i < 4; ++i)
            #pragma unroll
            for (int r2 = 0; r2 < 4; ++r2)
                smx[wnh][wm + i * 16 + q * 4 + r2] = mrow[i][r2];
    }
    __syncthreads();
    float M[4][4];
    #pragma unroll
    for (int i = 0; i < 4; ++i)
        #pragma unroll
        for (int r2 = 0; r2 < 4; ++r2)
            M[i][r2] = fmaxf(mrow[i][r2], smx[wnh ^ 1][wm + i * 16 + q * 4 + r2]);

    // sumexp against tile-row max
    float srow[4][4];
    #pragma unroll
    for (int i = 0; i < 4; ++i)
        #pragma unroll
        for (int r2 = 0; r2 < 4; ++r2) {
            float s = expf(acc[i][0][r2] - M[i][r2]) + expf(acc[i][1][r2] - M[i][r2])
                    + expf(acc[i][2][r2] - M[i][r2]) + expf(acc[i][3][r2] - M[i][r2]);
            #pragma unroll
            for (int mk = 1; mk <= 8; mk <<= 1)
                s += __shfl_xor(s, mk, 64);
            srow[i][r2] = s;
        }
    if (lrow == 0) {
        #pragma unroll
        for (int i = 0; i < 4; ++i)
            #pragma unroll
            for (int r2 = 0; r2 < 4; ++r2)
                ssm[wnh][wm + i * 16 + q * 4 + r2] = srow[i][r2];
    }
    __syncthreads();
    if (wnh == 0 && lrow == 0) {
        #pragma unroll
        for (int i = 0; i < 4; ++i)
            #pragma unroll
            for (int r2 = 0; r2 < 4; ++r2) {
                const int rl = wm + i * 16 + q * 4 + r2;
                const int R  = m0 + rl;
                tmax[(size_t)R * NTILES + nt] = M[i][r2];
                tsum[(size_t)R * NTILES + nt] = srow[i][r2] + ssm[1][rl];
            }
    }
}

// ---------- K3: combine tile partials -> nll; last block does the mean ----------
__global__ __launch_bounds__(256) void combine_kernel(
    const float* __restrict__ tmax,   // [NROWS][NTILES]
    const float* __restrict__ tsum,   // [NROWS][NTILES]
    const float* __restrict__ glab,   // [NROWS]
    float* __restrict__ nll,          // [NROWS] scratch
    float* __restrict__ out,          // [1]
    unsigned int* __restrict__ cnt)   // zeroed by K1
{
    __shared__ int s_last;
    const int tid = threadIdx.x;
    const int row = blockIdx.x * 256 + tid;

    const float4* mx4 = (const float4*)(tmax + (size_t)row * NTILES);
    const float4* sm4 = (const float4*)(tsum + (size_t)row * NTILES);
    float4 mv[8], sv[8];
    #pragma unroll
    for (int k = 0; k < 8; ++k) { mv[k] = mx4[k]; sv[k] = sm4[k]; }

    float gm = -1e30f;
    #pragma unroll
    for (int k = 0; k < 8; ++k)
        gm = fmaxf(gm, fmaxf(fmaxf(mv[k].x, mv[k].y), fmaxf(mv[k].z, mv[k].w)));

    float se = 0.f;
    #pragma unroll
    for (int k = 0; k < 8; ++k) {
        se += sv[k].x * expf(mv[k].x - gm);
        se += sv[k].y * expf(mv[k].y - gm);
        se += sv[k].z * expf(mv[k].z - gm);
        se += sv[k].w * expf(mv[k].w - gm);
    }
    nll[row] = logf(se) + gm - glab[row];

    if (tid == 0) {
        __threadfence();                               // publish this block's nll rows
        s_last = (atomicAdd(cnt, 1u) == (NROWS / 256) - 1);
    }
    __syncthreads();
    if (s_last) {
        __threadfence();                               // acquire
        float s = 0.f;
        #pragma unroll
        for (int t = 0; t < 4; ++t) s += nll[tid + t * 256];
        float tot = block_sum(s);
        if (tid == 0) out[0] = tot * (1.0f / NROWS);   // deterministic final sum
    }
}

// ---------- launch ----------
extern "C" void kernel_launch(void* const* d_in, const int* in_sizes, int n_in,
                              void* d_out, int out_size, void* d_ws, size_t ws_size,
                              hipStream_t stream) {
    const float* enc    = (const float*)d_in[0];
    const float* gamma  = (const float*)d_in[1];
    const float* beta   = (const float*)d_in[2];
    const float* W      = (const float*)d_in[3];
    const int*   heads  = (const int*)d_in[4];
    const int*   tails  = (const int*)d_in[5];
    const int*   labels = (const int*)d_in[6];
    float* out = (float*)d_out;

    char* ws = (char*)d_ws;
    unsigned short* embn = (unsigned short*)(ws);                         // 2 MB
    unsigned short* Wn   = (unsigned short*)(ws + (2u  << 20));           // 8 MB
    float* tmax          = (float*)        (ws + (10u << 20));            // 128 KB
    float* tsum          = (float*)        (ws + (10u << 20) + (128u<<10)); // 128 KB
    float* glab          = (float*)        (ws + (10u << 20) + (256u<<10)); // 4 KB
    float* nllbuf        = (float*)        (ws + (10u << 20) + (260u<<10)); // 4 KB
    unsigned int* cnt    = (unsigned int*) (ws + (10u << 20) + (264u<<10)); // 4 B

    fused_norm_kernel<<<NROWS + NC_, 256, 0, stream>>>(enc, gamma, beta, heads, tails, W, embn, Wn, cnt);
    dim3 g3(8, 32);
    gemm_ce_kernel <<<g3, 256, 0, stream>>>(embn, Wn, labels, tmax, tsum, glab);
    combine_kernel <<<NROWS / 256, 256, 0, stream>>>(tmax, tsum, glab, nllbuf, out, cnt);
}